// Round 17
// baseline (187.647 us; speedup 1.0000x reference)
//
#include <hip/hip_runtime.h>
#include <hip/hip_bf16.h>
#include <stdint.h>

// Problem constants
#define Bsz 32
#define Esz 64
#define Ssz 50
#define Dsz 300
#define Fsz 100
#define Hsz 100
#define WWIN 5

// Conv-as-GEMM geometry (per (b,e) block)
#define PX   328          // Xp row pitch in bf16 elems
#define PC   136          // conv_bf row pitch in bf16 elems
#define KT_CONV 50        // K' = 5 windows * 320 = 1600 -> 50 k-tiles of 32
#define NTILES  7         // N = 112 (100 padded)
#define MTILES  4         // M = 64  (50 padded)
#define NGRP 2214         // 54 rows * 41 groups-of-8

typedef __attribute__((ext_vector_type(8))) short bf16x8;
typedef __attribute__((ext_vector_type(8))) unsigned short u16x8;
typedef __attribute__((ext_vector_type(4))) float f32x4;
typedef _Float16 half2_t __attribute__((ext_vector_type(2)));

union UH32 { unsigned int u; half2_t v; };
union UH16 { _Float16 h; unsigned short u; };

__device__ __forceinline__ float sigmoid_fast(float x) {
    return 1.0f / (1.0f + __expf(-x));
}
__device__ __forceinline__ float tanhf_fast(float x) {
    const float ax = fabsf(x);
    const float e = __expf(2.0f * ax);
    const float t = 1.0f - 2.0f / (e + 1.0f);
    return copysignf(t, x);
}

__device__ __forceinline__ unsigned short f2bf(float x) {
    union { __hip_bfloat16 h; unsigned short u; } cv;
    cv.h = __float2bfloat16(x);
    return cv.u;
}
__device__ __forceinline__ unsigned int f2bf2(float lo, float hi) {
    union { __hip_bfloat162 h2; unsigned int u; } cv;
    cv.h2 = __float22bfloat162_rn(make_float2(lo, hi));
    return cv.u;
}
__device__ __forceinline__ float bf2f(unsigned short b) {
    union { uint32_t u; float f; } v; v.u = ((uint32_t)b) << 16;
    return v.f;
}
// quad all-reduce add: after this every lane of the quad holds the quad sum.
__device__ __forceinline__ float quad_ar(float x) {
    int r = __builtin_amdgcn_mov_dpp(__builtin_bit_cast(int, x), 0xB1, 0xf, 0xf, false); // [1,0,3,2]
    x += __builtin_bit_cast(float, r);
    r = __builtin_amdgcn_mov_dpp(__builtin_bit_cast(int, x), 0x4E, 0xf, 0xf, false);     // [2,3,0,1]
    x += __builtin_bit_cast(float, r);
    return x;
}

// ---------------------------------------------------------------------------
// Prep kernel: bf16 MFMA B-operands + quarter-split f16-packed Wh.
//  BtgC: [50][112][32] bf16   conv_k padded
//  BtgA: [4][112][32]  bf16   att1_mat padded
//  BtgW: [4][400][32]  bf16   lstm_W x-part rows (std gate order), n=400
//  BtgQ: [16][400][4]  uint   Wh half2 pairs; thread tid=(cell,g) owns
//                             k-quarter g (k=32g+2*k2q,+1), cols = 4 gates of cell
// ---------------------------------------------------------------------------
#define N_BTGC (KT_CONV * 112 * 32)   // 179200
#define N_BTGA (4 * 112 * 32)         // 14336
#define N_BTGW (4 * 400 * 32)         // 51200
#define N_BTGQ (16 * 400 * 4)         // 25600

__global__ __launch_bounds__(256) void prep_kernel(
    const float* __restrict__ conv_k, const float* __restrict__ att1_mat,
    const float* __restrict__ lstm_W,
    unsigned short* __restrict__ BtgC, unsigned short* __restrict__ BtgA,
    unsigned short* __restrict__ BtgW, unsigned int* __restrict__ BtgQ)
{
    const int total = N_BTGC + N_BTGA + N_BTGW + N_BTGQ;
    for (int i = blockIdx.x * 256 + threadIdx.x; i < total; i += gridDim.x * 256) {
        if (i < N_BTGC) {
            const int kt = i / (112 * 32);
            const int r  = i % (112 * 32);
            const int n  = r / 32;
            const int kk = r % 32;
            const int w  = kt / 10;
            const int d  = (kt % 10) * 32 + kk;
            float val = (d < Dsz && n < Fsz) ? conv_k[((size_t)w * Dsz + d) * Fsz + n] : 0.f;
            BtgC[i] = f2bf(val);
        } else if (i < N_BTGC + N_BTGA) {
            const int j  = i - N_BTGC;
            const int kt = j / (112 * 32);
            const int r  = j % (112 * 32);
            const int n  = r / 32;
            const int kk = r % 32;
            const int k  = kt * 32 + kk;
            float val = (k < Fsz && n < Fsz) ? att1_mat[(size_t)k * Fsz + n] : 0.f;
            BtgA[j] = f2bf(val);
        } else if (i < N_BTGC + N_BTGA + N_BTGW) {
            const int j  = i - N_BTGC - N_BTGA;
            const int kt = j / (400 * 32);
            const int r  = j % (400 * 32);
            const int n  = r / 32;
            const int kk = r % 32;
            const int k  = kt * 32 + kk;
            float val = (k < Fsz) ? lstm_W[(size_t)k * 400 + n] : 0.f;
            BtgW[j] = f2bf(val);
        } else {
            const int j   = i - N_BTGC - N_BTGA - N_BTGW;   // 0..25599
            const int c   = j & 3;                          // gate column 0..3
            const int r   = j >> 2;                         // k2q*400 + tid
            const int k2q = r / 400;
            const int tt  = r - k2q * 400;                  // destination thread
            const int g    = tt & 3;                        // its k-quarter
            const int cell = tt >> 2;
            const int k0 = 32 * g + 2 * k2q;
            const float v0 = (k0 < Hsz)
                ? lstm_W[(size_t)(Fsz + k0) * 400 + c * 100 + cell] : 0.f;
            const float v1 = (k0 + 1 < Hsz)
                ? lstm_W[(size_t)(Fsz + k0 + 1) * 400 + c * 100 + cell] : 0.f;
            union { _Float16 h[2]; unsigned int u; } cv;
            cv.h[0] = (_Float16)v0;
            cv.h[1] = (_Float16)v1;
            BtgQ[j] = cv.u;
        }
    }
}

// ---------------------------------------------------------------------------
// Conv K-loop helpers (N-split, register pipelines for A and B) — unchanged
// ---------------------------------------------------------------------------
template<int G>
__device__ __forceinline__ void conv_loadB(
    const unsigned short* __restrict__ BtgC, int boff0, int boff1, bool has1,
    bf16x8 (&bR)[5][2])
{
#pragma unroll
    for (int i = 0; i < 5; ++i) {
        const int kt = G * 5 + i;
        bR[i][0] = *reinterpret_cast<const bf16x8*>(BtgC + kt * 3584 + boff0);
        bR[i][1] = has1 ? *reinterpret_cast<const bf16x8*>(BtgC + kt * 3584 + boff1)
                        : (bf16x8)0;
    }
}

template<int KT>
__device__ __forceinline__ void conv_loadA(
    const unsigned short* b0p, const unsigned short* b1p,
    const int (&abase)[MTILES], bf16x8 (&a)[2][MTILES])
{
    constexpr int w   = KT / 10;
    constexpr int t   = KT % 10;
    constexpr int off = w * PX + t * 32;
#pragma unroll
    for (int mt = 0; mt < MTILES; ++mt) {
        a[0][mt] = *reinterpret_cast<const bf16x8*>(&b0p[abase[mt] + off]);
        a[1][mt] = *reinterpret_cast<const bf16x8*>(&b1p[abase[mt] + off]);
    }
}

__device__ __forceinline__ void mfma16(
    const bf16x8 (&a)[2][MTILES], const bf16x8 (&b)[2], bool has1,
    f32x4 (&acc)[2][MTILES][2])
{
    __builtin_amdgcn_s_setprio(1);
#pragma unroll
    for (int es = 0; es < 2; ++es) {
#pragma unroll
        for (int mt = 0; mt < MTILES; ++mt) {
            acc[es][mt][0] = __builtin_amdgcn_mfma_f32_16x16x32_bf16(a[es][mt], b[0], acc[es][mt][0], 0, 0, 0);
            if (has1)
                acc[es][mt][1] = __builtin_amdgcn_mfma_f32_16x16x32_bf16(a[es][mt], b[1], acc[es][mt][1], 0, 0, 0);
        }
    }
    __builtin_amdgcn_s_setprio(0);
}

template<int KT>
__device__ __forceinline__ void conv_kt(
    const unsigned short* b0p, const unsigned short* b1p,
    const int (&abase)[MTILES], bool has1, const bf16x8 (&b)[2],
    bf16x8 (&aX)[2][MTILES], bf16x8 (&aY)[2][MTILES],
    f32x4 (&acc)[2][MTILES][2])
{
    constexpr bool even = (KT % 2) == 0;
    if constexpr (KT + 1 < KT_CONV) {
        if constexpr (even) conv_loadA<KT + 1>(b0p, b1p, abase, aY);
        else                conv_loadA<KT + 1>(b0p, b1p, abase, aX);
    }
    if constexpr (even) mfma16(aX, b, has1, acc);
    else                mfma16(aY, b, has1, acc);
}

template<int G>
__device__ __forceinline__ void conv_group(
    const unsigned short* b0p, const unsigned short* b1p,
    const int (&abase)[MTILES], bool has1, const bf16x8 (&bR)[5][2],
    bf16x8 (&aX)[2][MTILES], bf16x8 (&aY)[2][MTILES],
    f32x4 (&acc)[2][MTILES][2])
{
    conv_kt<G * 5 + 0>(b0p, b1p, abase, has1, bR[0], aX, aY, acc);
    conv_kt<G * 5 + 1>(b0p, b1p, abase, has1, bR[1], aX, aY, acc);
    conv_kt<G * 5 + 2>(b0p, b1p, abase, has1, bR[2], aX, aY, acc);
    conv_kt<G * 5 + 3>(b0p, b1p, abase, has1, bR[3], aX, aY, acc);
    conv_kt<G * 5 + 4>(b0p, b1p, abase, has1, bR[4], aX, aY, acc);
}

template<int KT>
__device__ __forceinline__ void att_loadA(
    const unsigned short* b0p, const unsigned short* b1p,
    const int (&abase2)[MTILES], bf16x8 (&a)[2][MTILES])
{
    constexpr int off = KT * 32;
#pragma unroll
    for (int mt = 0; mt < MTILES; ++mt) {
        a[0][mt] = *reinterpret_cast<const bf16x8*>(&b0p[abase2[mt] + off]);
        a[1][mt] = *reinterpret_cast<const bf16x8*>(&b1p[abase2[mt] + off]);
    }
}

// ---------------------------------------------------------------------------
// Kernel 1: TWO essays per block. conv via bf16 MFMA + att1 pooling. (R16)
// ---------------------------------------------------------------------------
__global__ __launch_bounds__(256, 2) void conv_att1_kernel(
    const float* __restrict__ essays,
    const unsigned short* __restrict__ BtgC,
    const unsigned short* __restrict__ BtgA,
    const float* __restrict__ conv_b,
    const float* __restrict__ att1_bias,
    const float* __restrict__ att1_vec,
    unsigned short* __restrict__ sent_bf)
{
    __shared__ __align__(16) unsigned short buf[2][54 * PX];   // 70848 B
    __shared__ float u_s[2][64];
    __shared__ float alpha_s[2][64];

    const int be0 = blockIdx.x * 2;
    const int tid = threadIdx.x;
    const int lane = tid & 63;
    const int wid  = tid >> 6;
    const int ln   = lane & 15;
    const int qd   = lane >> 4;

    if (tid < 128) u_s[tid >> 6][tid & 63] = 0.f;

    const int nt0 = wid;
    const int nt1 = wid + 4;
    const bool has1 = (nt1 < NTILES);
    const int boff0 = (nt0 * 16 + ln) * 32 + 8 * qd;
    const int boff1 = (nt1 * 16 + ln) * 32 + 8 * qd;

    int abase[MTILES];
#pragma unroll
    for (int mt = 0; mt < MTILES; ++mt) {
        const int m = mt * 16 + ln;
        abase[mt] = (m < Ssz ? m : Ssz - 1) * PX + 8 * qd;
    }

    bf16x8 bX[5][2], bY[5][2];
    conv_loadB<0>(BtgC, boff0, boff1, has1, bX);
    conv_loadB<1>(BtgC, boff0, boff1, has1, bY);

#pragma unroll
    for (int es = 0; es < 2; ++es) {
        const float* in_g = essays + (size_t)(be0 + es) * (Ssz * Dsz);
        float4 va[9], vb[9];
        int rr[9], cc[9];
        bool hv[9], fv[9], gv[9];
#pragma unroll
        for (int it = 0; it < 9; ++it) {
            const int g  = tid + it * 256;
            const int r  = g / 41;
            const int c8 = (g - r * 41) * 8;
            const int s  = r - 2;
            gv[it] = (g < NGRP);
            hv[it] = gv[it] && (s >= 0) && (s < Ssz) && (c8 < Dsz);
            fv[it] = hv[it] && (c8 + 8 <= Dsz);
            const float* base = in_g + (hv[it] ? (s * Dsz + c8) : 0);
            va[it] = *reinterpret_cast<const float4*>(base);
            vb[it] = *reinterpret_cast<const float4*>(fv[it] ? base + 4 : base);
            rr[it] = r; cc[it] = c8;
        }
#pragma unroll
        for (int it = 0; it < 9; ++it) {
            if (!gv[it]) continue;
            const float e0 = hv[it] ? va[it].x : 0.f;
            const float e1 = hv[it] ? va[it].y : 0.f;
            const float e2 = hv[it] ? va[it].z : 0.f;
            const float e3 = hv[it] ? va[it].w : 0.f;
            const float e4 = fv[it] ? vb[it].x : 0.f;
            const float e5 = fv[it] ? vb[it].y : 0.f;
            const float e6 = fv[it] ? vb[it].z : 0.f;
            const float e7 = fv[it] ? vb[it].w : 0.f;
            uint4 o;
            o.x = f2bf2(e0, e1);
            o.y = f2bf2(e2, e3);
            o.z = f2bf2(e4, e5);
            o.w = f2bf2(e6, e7);
            *reinterpret_cast<uint4*>(&buf[es][rr[it] * PX + cc[it]]) = o;
        }
    }
    __syncthreads();

    const unsigned short* b0p = buf[0];
    const unsigned short* b1p = buf[1];

    f32x4 acc[2][MTILES][2];
#pragma unroll
    for (int es = 0; es < 2; ++es)
#pragma unroll
        for (int mt = 0; mt < MTILES; ++mt) { acc[es][mt][0] = (f32x4)0.f; acc[es][mt][1] = (f32x4)0.f; }

    {
        bf16x8 aX[2][MTILES], aY[2][MTILES];
        conv_loadA<0>(b0p, b1p, abase, aX);
        conv_group<0>(b0p, b1p, abase, has1, bX, aX, aY, acc);
        conv_loadB<2>(BtgC, boff0, boff1, has1, bX);
        conv_group<1>(b0p, b1p, abase, has1, bY, aX, aY, acc);
        conv_loadB<3>(BtgC, boff0, boff1, has1, bY);
        conv_group<2>(b0p, b1p, abase, has1, bX, aX, aY, acc);
        conv_loadB<4>(BtgC, boff0, boff1, has1, bX);
        conv_group<3>(b0p, b1p, abase, has1, bY, aX, aY, acc);
        conv_loadB<5>(BtgC, boff0, boff1, has1, bY);
        conv_group<4>(b0p, b1p, abase, has1, bX, aX, aY, acc);
        conv_loadB<6>(BtgC, boff0, boff1, has1, bX);
        conv_group<5>(b0p, b1p, abase, has1, bY, aX, aY, acc);
        conv_loadB<7>(BtgC, boff0, boff1, has1, bY);
        conv_group<6>(b0p, b1p, abase, has1, bX, aX, aY, acc);
        conv_loadB<8>(BtgC, boff0, boff1, has1, bX);
        conv_group<7>(b0p, b1p, abase, has1, bY, aX, aY, acc);
        conv_loadB<9>(BtgC, boff0, boff1, has1, bY);
        conv_group<8>(b0p, b1p, abase, has1, bX, aX, aY, acc);
        conv_group<9>(b0p, b1p, abase, has1, bY, aX, aY, acc);
    }

    bf16x8 a1b[4][2];
#pragma unroll
    for (int kt = 0; kt < 4; ++kt) {
        a1b[kt][0] = *reinterpret_cast<const bf16x8*>(BtgA + kt * 3584 + boff0);
        a1b[kt][1] = has1 ? *reinterpret_cast<const bf16x8*>(BtgA + kt * 3584 + boff1)
                          : (bf16x8)0;
    }
    __syncthreads();

    {
        const float bias0 = conv_b[nt0 * 16 + ln];
        const int n_g1 = nt1 * 16 + ln;
        const bool g1ok = has1 && (n_g1 < Fsz);
        const float bias1 = g1ok ? conv_b[n_g1] : 0.f;
#pragma unroll
        for (int es = 0; es < 2; ++es) {
#pragma unroll
            for (int mt = 0; mt < MTILES; ++mt) {
#pragma unroll
                for (int j = 0; j < 4; ++j) {
                    const int m_row = mt * 16 + qd * 4 + j;
                    buf[es][m_row * PC + nt0 * 16 + ln] = f2bf(fmaxf(acc[es][mt][0][j] + bias0, 0.f));
                    if (g1ok)
                        buf[es][m_row * PC + n_g1] = f2bf(fmaxf(acc[es][mt][1][j] + bias1, 0.f));
                }
            }
        }
    }
    for (int idx = tid; idx < 2 * 64 * 2; idx += 256) {
        const int es = idx >> 7;
        const int r2 = idx & 127;
        const int row = r2 >> 1;
        const int c = 112 + (r2 & 1) * 8;
        *reinterpret_cast<u16x8*>(&buf[es][row * PC + c]) = (u16x8)0;
    }
    __syncthreads();

    f32x4 acc2[2][MTILES][2];
#pragma unroll
    for (int es = 0; es < 2; ++es)
#pragma unroll
        for (int mt = 0; mt < MTILES; ++mt) { acc2[es][mt][0] = (f32x4)0.f; acc2[es][mt][1] = (f32x4)0.f; }

    {
        int abase2[MTILES];
#pragma unroll
        for (int mt = 0; mt < MTILES; ++mt) abase2[mt] = (mt * 16 + ln) * PC + 8 * qd;

        bf16x8 aX[2][MTILES], aY[2][MTILES];
        att_loadA<0>(b0p, b1p, abase2, aX);
        att_loadA<1>(b0p, b1p, abase2, aY);
        mfma16(aX, a1b[0], has1, acc2);
        att_loadA<2>(b0p, b1p, abase2, aX);
        mfma16(aY, a1b[1], has1, acc2);
        att_loadA<3>(b0p, b1p, abase2, aY);
        mfma16(aX, a1b[2], has1, acc2);
        mfma16(aY, a1b[3], has1, acc2);
    }

    {
        const int g0 = nt0 * 16 + ln;
        const float b1v0 = att1_bias[g0];
        const float vv0  = att1_vec[g0];
        const int g1 = nt1 * 16 + ln;
        const bool g1v = has1 && (g1 < Fsz);
        const float b1v1 = g1v ? att1_bias[g1] : 0.f;
        const float vv1  = g1v ? att1_vec[g1]  : 0.f;
#pragma unroll
        for (int es = 0; es < 2; ++es) {
#pragma unroll
            for (int mt = 0; mt < MTILES; ++mt) {
#pragma unroll
                for (int j = 0; j < 4; ++j) {
                    const int m_row = mt * 16 + qd * 4 + j;
                    float val = 0.f;
                    if (m_row < Ssz) {
                        val = tanhf_fast(acc2[es][mt][0][j] + b1v0) * vv0;
                        if (g1v) val += tanhf_fast(acc2[es][mt][1][j] + b1v1) * vv1;
                    }
                    val += __shfl_xor(val, 1);
                    val += __shfl_xor(val, 2);
                    val += __shfl_xor(val, 4);
                    val += __shfl_xor(val, 8);
                    if (ln == 0 && m_row < Ssz) atomicAdd(&u_s[es][m_row], val);
                }
            }
        }
    }
    __syncthreads();

    if (wid < 2) {
        const float uv = (lane < Ssz) ? u_s[wid][lane] : -1e30f;
        float m = uv;
#pragma unroll
        for (int off = 32; off > 0; off >>= 1) m = fmaxf(m, __shfl_xor(m, off));
        float e = (lane < Ssz) ? __expf(uv - m) : 0.f;
        float sum = e;
#pragma unroll
        for (int off = 32; off > 0; off >>= 1) sum += __shfl_xor(sum, off);
        alpha_s[wid][lane] = e / sum;
    }
    __syncthreads();

    {
        const int es = tid >> 7;
        const int f  = tid & 127;
        unsigned short v = 0;
        if (f < Fsz) {
            float a = 0.f;
            for (int s = 0; s < Ssz; ++s) a += alpha_s[es][s] * bf2f(buf[es][s * PC + f]);
            v = f2bf(a);
        }
        sent_bf[(size_t)(be0 + es) * 128 + f] = v;
    }
}

// ---------------------------------------------------------------------------
// Kernel 1b: xpartB[row*400 + gi] = sent_bf @ Wx + lstm_b, row = b*64+t,
// gi = cell*4+gate (quad-interleaved, matches lstm tid order)
// ---------------------------------------------------------------------------
__global__ __launch_bounds__(256) void xpart_kernel(
    const unsigned short* __restrict__ sent_bf, // [2048][128]
    const unsigned short* __restrict__ BtgW,    // [4][400][32] (std gate order)
    const float* __restrict__ lstm_b,           // [400]
    float* __restrict__ xpartB)                 // [2048][400] (b*64+t, gi)
{
    const int wid  = threadIdx.x >> 6;
    const int mt   = blockIdx.x * 4 + wid;      // 0..127
    const int lane = threadIdx.x & 63;
    const int ln   = lane & 15;
    const int qd   = lane >> 4;
    const int m0   = mt * 16;

    f32x4 acc[25];
#pragma unroll
    for (int nt = 0; nt < 25; ++nt) acc[nt] = (f32x4)0.f;

#pragma unroll
    for (int kt = 0; kt < 4; ++kt) {
        const bf16x8 a = *reinterpret_cast<const bf16x8*>(
            sent_bf + (size_t)(m0 + ln) * 128 + kt * 32 + 8 * qd);
#pragma unroll
        for (int nt = 0; nt < 25; ++nt) {
            const bf16x8 b = *reinterpret_cast<const bf16x8*>(
                BtgW + ((size_t)kt * 400 + nt * 16 + ln) * 32 + 8 * qd);
            acc[nt] = __builtin_amdgcn_mfma_f32_16x16x32_bf16(a, b, acc[nt], 0, 0, 0);
        }
    }

#pragma unroll
    for (int nt = 0; nt < 25; ++nt) {
        const int col = nt * 16 + ln;               // standard gate order
        const int gate = col / 100;
        const int cell = col - gate * 100;
        const float bias = lstm_b[col];
        const int gi = cell * 4 + gate;
#pragma unroll
        for (int j = 0; j < 4; ++j) {
            const int row = m0 + qd * 4 + j;        // b*64 + t
            xpartB[(size_t)row * 400 + gi] = acc[nt][j] + bias;
        }
    }
}

// ---------------------------------------------------------------------------
// Kernel 2: fused LSTM + att2, one block per batch. Quarter-split gate dot:
// thread (cell,g) reads ONLY its h-quarter (4 x ds_read_b128 at 80B-stride
// banks), computes partials for all 4 gates of its cell (64 v_dot2), then
// DPP quad-allreduce gives all lanes all 4 z values. 1 barrier/step.
// ---------------------------------------------------------------------------
__global__ __launch_bounds__(448) void lstm_att2_kernel(
    const float* __restrict__ xpartB,      // [2048][400] (b*64+t, gi) +bias
    const unsigned int* __restrict__ BtgQ, // [16][400][4] quarter-split Wh
    const float* __restrict__ att2_mat,
    const float* __restrict__ att2_bias,
    const float* __restrict__ att2_vec,
    const float* __restrict__ dense_w,
    const float* __restrict__ dense_b,
    float* __restrict__ out)
{
    __shared__ __align__(16) float xp_lds[Esz * 400];        // 102400 B
    __shared__ __align__(16) float hist[Esz * Hsz];          // 25600 B
    __shared__ __align__(16) unsigned short h16[2][160];     // 640 B (quarters at 40-elem stride)
    __shared__ float u2_s[Esz];
    __shared__ float alpha2_s[Esz];
    __shared__ float repr_s[Hsz];

    const int b   = blockIdx.x;
    const int tid = threadIdx.x;
    const bool actv = tid < 400;
    const int cell = tid >> 2;
    const int g    = tid & 3;

    // ---- stage xpart for this batch into LDS (6400 float4, coalesced) ----
    {
        const float4* src = reinterpret_cast<const float4*>(xpartB + (size_t)b * Esz * 400);
        float4* dst = reinterpret_cast<float4*>(xp_lds);
        for (int i = tid; i < Esz * 100; i += 448) dst[i] = src[i];
    }

    // ---- quarter-split Wh: 16 coalesced uint4 loads (64 VGPR) ----
    uint4 wq[16];
    if (actv) {
#pragma unroll
        for (int q = 0; q < 16; ++q)
            wq[q] = *reinterpret_cast<const uint4*>(BtgQ + ((size_t)q * 400 + tid) * 4);
    }
    if (tid < 160) { h16[0][tid] = 0; h16[1][tid] = 0; }
    float cstate = 0.f;
    __syncthreads();

    // ---- recurrence: 1 barrier/step, no global ops ----
    for (int t = 0; t < Esz; ++t) {
        if (actv) {
            // own h quarter: 4 x b128 at element offset g*40 (byte g*80 -> disjoint banks)
            const uint4* hq = reinterpret_cast<const uint4*>(&h16[t & 1][g * 40]);
            // all 4 xp values of this cell in one b128
            const float4 xp4 = *reinterpret_cast<const float4*>(&xp_lds[t * 400 + cell * 4]);

            float p0 = 0.f, p1 = 0.f, p2 = 0.f, p3 = 0.f;
#pragma unroll
            for (int j4 = 0; j4 < 4; ++j4) {
                const uint4 hv = hq[j4];
                const unsigned int hu0 = hv.x, hu1 = hv.y, hu2 = hv.z, hu3 = hv.w;
#pragma unroll
                for (int q = 0; q < 4; ++q) {
                    UH32 hh;
                    hh.u = (q == 0) ? hu0 : (q == 1) ? hu1 : (q == 2) ? hu2 : hu3;
                    const uint4 wv = wq[j4 * 4 + q];
                    UH32 w0, w1, w2, w3;
                    w0.u = wv.x; w1.u = wv.y; w2.u = wv.z; w3.u = wv.w;
                    p0 = __builtin_amdgcn_fdot2(w0.v, hh.v, p0, false);
                    p1 = __builtin_amdgcn_fdot2(w1.v, hh.v, p1, false);
                    p2 = __builtin_amdgcn_fdot2(w2.v, hh.v, p2, false);
                    p3 = __builtin_amdgcn_fdot2(w3.v, hh.v, p3, false);
                }
            }
            // quad allreduce: every lane gets full dot for each gate
            const float zi = quad_ar(p0) + xp4.x;
            const float zj = quad_ar(p1) + xp4.y;
            const float zf = quad_ar(p2) + xp4.z;
            const float zo = quad_ar(p3) + xp4.w;

            cstate = cstate * sigmoid_fast(zf + 1.0f) + sigmoid_fast(zi) * tanhf_fast(zj);
            const float h = sigmoid_fast(zo) * tanhf_fast(cstate);
            if (g == 0) {
                UH16 cv; cv.h = (_Float16)h;
                h16[(t + 1) & 1][(cell >> 5) * 40 + (cell & 31)] = cv.u;
                hist[t * Hsz + cell] = h;
            }
        }
        __syncthreads();
    }

    // ---- att2 on LDS hist; w2 aliases xp_lds (dead after recurrence) ----
    float* w2_s = xp_lds;
    for (int idx = tid; idx < Esz * Hsz; idx += 448) {
        const int e = idx / Hsz;
        const int gg = idx - e * Hsz;
        const float* lp = hist + e * Hsz;
        float a0 = 0.f, a1 = 0.f, a2 = 0.f, a3 = 0.f;
        for (int k = 0; k < Hsz; k += 4) {
            a0 += lp[k + 0] * att2_mat[(k + 0) * Hsz + gg];
            a1 += lp[k + 1] * att2_mat[(k + 1) * Hsz + gg];
            a2 += lp[k + 2] * att2_mat[(k + 2) * Hsz + gg];
            a3 += lp[k + 3] * att2_mat[(k + 3) * Hsz + gg];
        }
        w2_s[idx] = tanhf_fast(att2_bias[gg] + ((a0 + a1) + (a2 + a3))) * att2_vec[gg];
    }
    __syncthreads();

    if (tid < Esz) {
        float acc = 0.f;
        const float* wpp = w2_s + tid * Hsz;
        for (int gg = 0; gg < Hsz; ++gg) acc += wpp[gg];
        u2_s[tid] = acc;
    }
    __syncthreads();

    if (tid < 64) {
        const float uv = u2_s[tid];
        float m = uv;
#pragma unroll
        for (int off = 32; off > 0; off >>= 1) m = fmaxf(m, __shfl_xor(m, off));
        float e = __expf(uv - m);
        float sum = e;
#pragma unroll
        for (int off = 32; off > 0; off >>= 1) sum += __shfl_xor(sum, off);
        alpha2_s[tid] = e / sum;
    }
    __syncthreads();

    if (tid < Hsz) {
        float acc = 0.f;
        for (int e = 0; e < Esz; ++e) acc += alpha2_s[e] * hist[e * Hsz + tid];
        repr_s[tid] = acc;
    }
    __syncthreads();

    if (tid == 0) {
        float acc = dense_b[0];
        for (int hh = 0; hh < Hsz; ++hh) acc += repr_s[hh] * dense_w[hh];
        out[b] = sigmoid_fast(acc);
    }
}

// ---------------------------------------------------------------------------
extern "C" void kernel_launch(void* const* d_in, const int* in_sizes, int n_in,
                              void* d_out, int out_size, void* d_ws, size_t ws_size,
                              hipStream_t stream) {
    const float* essays    = (const float*)d_in[0];
    const float* conv_k    = (const float*)d_in[1];
    const float* conv_b    = (const float*)d_in[2];
    const float* att1_mat  = (const float*)d_in[3];
    const float* att1_bias = (const float*)d_in[4];
    const float* att1_vec  = (const float*)d_in[5];
    const float* lstm_W    = (const float*)d_in[6];
    const float* lstm_b    = (const float*)d_in[7];
    const float* att2_mat  = (const float*)d_in[8];
    const float* att2_bias = (const float*)d_in[9];
    const float* att2_vec  = (const float*)d_in[10];
    const float* dense_w   = (const float*)d_in[11];
    const float* dense_b   = (const float*)d_in[12];

    float* out = (float*)d_out;

    // workspace layout (256B-aligned chunks)
    char* ws = (char*)d_ws;
    unsigned short* sent_bf = (unsigned short*)ws;              // 524288 B
    float* xpartB = (float*)(ws + 524288);                      // 3276800 B
    unsigned short* BtgC = (unsigned short*)(ws + 3801088);     // 358400 B
    unsigned short* BtgA = (unsigned short*)(ws + 4159488);     // 28672 B
    unsigned short* BtgW = (unsigned short*)(ws + 4188160);     // 102400 B
    unsigned int*   BtgQ = (unsigned int*)(ws + 4290560);       // 102400 B

    prep_kernel<<<512, 256, 0, stream>>>(conv_k, att1_mat, lstm_W, BtgC, BtgA, BtgW, BtgQ);
    conv_att1_kernel<<<Bsz * Esz / 2, 256, 0, stream>>>(
        essays, BtgC, BtgA, conv_b, att1_bias, att1_vec, sent_bf);
    xpart_kernel<<<32, 256, 0, stream>>>(sent_bf, BtgW, lstm_b, xpartB);
    lstm_att2_kernel<<<Bsz, 448, 0, stream>>>(
        xpartB, BtgQ, att2_mat, att2_bias, att2_vec, dense_w, dense_b, out);
}

// Round 18
// 185.901 us; speedup vs baseline: 1.0094x; 1.0094x over previous
//
#include <hip/hip_runtime.h>
#include <hip/hip_bf16.h>
#include <stdint.h>

// Problem constants
#define Bsz 32
#define Esz 64
#define Ssz 50
#define Dsz 300
#define Fsz 100
#define Hsz 100
#define WWIN 5

// Conv-as-GEMM geometry (per (b,e) block)
#define PX   328          // Xp row pitch in bf16 elems
#define PC   136          // conv_bf row pitch in bf16 elems
#define KT_CONV 50        // K' = 5 windows * 320 = 1600 -> 50 k-tiles of 32
#define NTILES  7         // N = 112 (100 padded)
#define MTILES  4         // M = 64  (50 padded)
#define NGRP 2214         // 54 rows * 41 groups-of-8

typedef __attribute__((ext_vector_type(8))) short bf16x8;
typedef __attribute__((ext_vector_type(8))) unsigned short u16x8;
typedef __attribute__((ext_vector_type(4))) float f32x4;
typedef _Float16 half2_t __attribute__((ext_vector_type(2)));

union UH32 { unsigned int u; half2_t v; };
union UH16 { _Float16 h; unsigned short u; };

__device__ __forceinline__ float sigmoid_fast(float x) {
    return 1.0f / (1.0f + __expf(-x));
}
__device__ __forceinline__ float tanhf_fast(float x) {
    const float ax = fabsf(x);
    const float e = __expf(2.0f * ax);
    const float t = 1.0f - 2.0f / (e + 1.0f);
    return copysignf(t, x);
}

__device__ __forceinline__ unsigned short f2bf(float x) {
    union { __hip_bfloat16 h; unsigned short u; } cv;
    cv.h = __float2bfloat16(x);
    return cv.u;
}
__device__ __forceinline__ unsigned int f2bf2(float lo, float hi) {
    union { __hip_bfloat162 h2; unsigned int u; } cv;
    cv.h2 = __float22bfloat162_rn(make_float2(lo, hi));
    return cv.u;
}
__device__ __forceinline__ float bf2f(unsigned short b) {
    union { uint32_t u; float f; } v; v.u = ((uint32_t)b) << 16;
    return v.f;
}
__device__ __forceinline__ float dpp_bcast(float z, const int sel) {
    // quad_perm broadcast of quad lane sel (0..3); VALU op, no LDS pipe.
    int r;
    switch (sel) {
        case 0: r = __builtin_amdgcn_mov_dpp(__builtin_bit_cast(int, z), 0x00, 0xf, 0xf, false); break;
        case 1: r = __builtin_amdgcn_mov_dpp(__builtin_bit_cast(int, z), 0x55, 0xf, 0xf, false); break;
        case 2: r = __builtin_amdgcn_mov_dpp(__builtin_bit_cast(int, z), 0xaa, 0xf, 0xf, false); break;
        default: r = __builtin_amdgcn_mov_dpp(__builtin_bit_cast(int, z), 0xff, 0xf, 0xf, false); break;
    }
    return __builtin_bit_cast(float, r);
}

// ---------------------------------------------------------------------------
// Prep kernel: bf16 MFMA B-operands + f16-packed Wh.
//  BtgC: [50][112][32] bf16   conv_k padded
//  BtgA: [4][112][32]  bf16   att1_mat padded
//  BtgW: [4][400][32]  bf16   lstm_W x-part rows (std gate order), n=400
//  BtgP: [52][400]     uint   Wh packed half2 pairs, col = 4*cell+gate order
// ---------------------------------------------------------------------------
#define N_BTGC (KT_CONV * 112 * 32)   // 179200
#define N_BTGA (4 * 112 * 32)         // 14336
#define N_BTGW (4 * 400 * 32)         // 51200
#define N_BTGP (52 * 400)             // 20800

__global__ __launch_bounds__(256) void prep_kernel(
    const float* __restrict__ conv_k, const float* __restrict__ att1_mat,
    const float* __restrict__ lstm_W,
    unsigned short* __restrict__ BtgC, unsigned short* __restrict__ BtgA,
    unsigned short* __restrict__ BtgW, unsigned int* __restrict__ BtgP)
{
    const int total = N_BTGC + N_BTGA + N_BTGW + N_BTGP;
    for (int i = blockIdx.x * 256 + threadIdx.x; i < total; i += gridDim.x * 256) {
        if (i < N_BTGC) {
            const int kt = i / (112 * 32);
            const int r  = i % (112 * 32);
            const int n  = r / 32;
            const int kk = r % 32;
            const int w  = kt / 10;
            const int d  = (kt % 10) * 32 + kk;
            float val = (d < Dsz && n < Fsz) ? conv_k[((size_t)w * Dsz + d) * Fsz + n] : 0.f;
            BtgC[i] = f2bf(val);
        } else if (i < N_BTGC + N_BTGA) {
            const int j  = i - N_BTGC;
            const int kt = j / (112 * 32);
            const int r  = j % (112 * 32);
            const int n  = r / 32;
            const int kk = r % 32;
            const int k  = kt * 32 + kk;
            float val = (k < Fsz && n < Fsz) ? att1_mat[(size_t)k * Fsz + n] : 0.f;
            BtgA[j] = f2bf(val);
        } else if (i < N_BTGC + N_BTGA + N_BTGW) {
            const int j  = i - N_BTGC - N_BTGA;
            const int kt = j / (400 * 32);
            const int r  = j % (400 * 32);
            const int n  = r / 32;
            const int kk = r % 32;
            const int k  = kt * 32 + kk;
            float val = (k < Fsz) ? lstm_W[(size_t)k * 400 + n] : 0.f;
            BtgW[j] = f2bf(val);
        } else {
            const int j   = i - N_BTGC - N_BTGA - N_BTGW;
            const int k2  = j / 400;
            const int col = j - k2 * 400;
            const int gate = col & 3;
            const int cell = col >> 2;
            const int src  = gate * 100 + cell;
            const int k0 = 2 * k2, k1 = 2 * k2 + 1;
            const float v0 = (k0 < Hsz) ? lstm_W[(size_t)(Fsz + k0) * 400 + src] : 0.f;
            const float v1 = (k1 < Hsz) ? lstm_W[(size_t)(Fsz + k1) * 400 + src] : 0.f;
            union { _Float16 h[2]; unsigned int u; } cv;
            cv.h[0] = (_Float16)v0;
            cv.h[1] = (_Float16)v1;
            BtgP[j] = cv.u;
        }
    }
}

// ---------------------------------------------------------------------------
// Conv K-loop helpers (N-split, register pipelines for A and B)
// ---------------------------------------------------------------------------
template<int G>
__device__ __forceinline__ void conv_loadB(
    const unsigned short* __restrict__ BtgC, int boff0, int boff1, bool has1,
    bf16x8 (&bR)[5][2])
{
#pragma unroll
    for (int i = 0; i < 5; ++i) {
        const int kt = G * 5 + i;
        bR[i][0] = *reinterpret_cast<const bf16x8*>(BtgC + kt * 3584 + boff0);
        bR[i][1] = has1 ? *reinterpret_cast<const bf16x8*>(BtgC + kt * 3584 + boff1)
                        : (bf16x8)0;
    }
}

template<int KT>
__device__ __forceinline__ void conv_loadA(
    const unsigned short* b0p, const unsigned short* b1p,
    const int (&abase)[MTILES], bf16x8 (&a)[2][MTILES])
{
    constexpr int w   = KT / 10;
    constexpr int t   = KT % 10;
    constexpr int off = w * PX + t * 32;
#pragma unroll
    for (int mt = 0; mt < MTILES; ++mt) {
        a[0][mt] = *reinterpret_cast<const bf16x8*>(&b0p[abase[mt] + off]);
        a[1][mt] = *reinterpret_cast<const bf16x8*>(&b1p[abase[mt] + off]);
    }
}

__device__ __forceinline__ void mfma16(
    const bf16x8 (&a)[2][MTILES], const bf16x8 (&b)[2], bool has1,
    f32x4 (&acc)[2][MTILES][2])
{
    __builtin_amdgcn_s_setprio(1);
#pragma unroll
    for (int es = 0; es < 2; ++es) {
#pragma unroll
        for (int mt = 0; mt < MTILES; ++mt) {
            acc[es][mt][0] = __builtin_amdgcn_mfma_f32_16x16x32_bf16(a[es][mt], b[0], acc[es][mt][0], 0, 0, 0);
            if (has1)
                acc[es][mt][1] = __builtin_amdgcn_mfma_f32_16x16x32_bf16(a[es][mt], b[1], acc[es][mt][1], 0, 0, 0);
        }
    }
    __builtin_amdgcn_s_setprio(0);
}

template<int KT>
__device__ __forceinline__ void conv_kt(
    const unsigned short* b0p, const unsigned short* b1p,
    const int (&abase)[MTILES], bool has1, const bf16x8 (&b)[2],
    bf16x8 (&aX)[2][MTILES], bf16x8 (&aY)[2][MTILES],
    f32x4 (&acc)[2][MTILES][2])
{
    constexpr bool even = (KT % 2) == 0;
    if constexpr (KT + 1 < KT_CONV) {
        if constexpr (even) conv_loadA<KT + 1>(b0p, b1p, abase, aY);
        else                conv_loadA<KT + 1>(b0p, b1p, abase, aX);
    }
    if constexpr (even) mfma16(aX, b, has1, acc);
    else                mfma16(aY, b, has1, acc);
}

template<int G>
__device__ __forceinline__ void conv_group(
    const unsigned short* b0p, const unsigned short* b1p,
    const int (&abase)[MTILES], bool has1, const bf16x8 (&bR)[5][2],
    bf16x8 (&aX)[2][MTILES], bf16x8 (&aY)[2][MTILES],
    f32x4 (&acc)[2][MTILES][2])
{
    conv_kt<G * 5 + 0>(b0p, b1p, abase, has1, bR[0], aX, aY, acc);
    conv_kt<G * 5 + 1>(b0p, b1p, abase, has1, bR[1], aX, aY, acc);
    conv_kt<G * 5 + 2>(b0p, b1p, abase, has1, bR[2], aX, aY, acc);
    conv_kt<G * 5 + 3>(b0p, b1p, abase, has1, bR[3], aX, aY, acc);
    conv_kt<G * 5 + 4>(b0p, b1p, abase, has1, bR[4], aX, aY, acc);
}

template<int KT>
__device__ __forceinline__ void att_loadA(
    const unsigned short* b0p, const unsigned short* b1p,
    const int (&abase2)[MTILES], bf16x8 (&a)[2][MTILES])
{
    constexpr int off = KT * 32;
#pragma unroll
    for (int mt = 0; mt < MTILES; ++mt) {
        a[0][mt] = *reinterpret_cast<const bf16x8*>(&b0p[abase2[mt] + off]);
        a[1][mt] = *reinterpret_cast<const bf16x8*>(&b1p[abase2[mt] + off]);
    }
}

// ---------------------------------------------------------------------------
// Kernel 1: TWO essays per block. conv via bf16 MFMA + att1 pooling.
// ---------------------------------------------------------------------------
__global__ __launch_bounds__(256, 2) void conv_att1_kernel(
    const float* __restrict__ essays,
    const unsigned short* __restrict__ BtgC,
    const unsigned short* __restrict__ BtgA,
    const float* __restrict__ conv_b,
    const float* __restrict__ att1_bias,
    const float* __restrict__ att1_vec,
    unsigned short* __restrict__ sent_bf)
{
    __shared__ __align__(16) unsigned short buf[2][54 * PX];   // 70848 B
    __shared__ float u_s[2][64];
    __shared__ float alpha_s[2][64];

    const int be0 = blockIdx.x * 2;
    const int tid = threadIdx.x;
    const int lane = tid & 63;
    const int wid  = tid >> 6;
    const int ln   = lane & 15;
    const int qd   = lane >> 4;

    if (tid < 128) u_s[tid >> 6][tid & 63] = 0.f;

    const int nt0 = wid;
    const int nt1 = wid + 4;
    const bool has1 = (nt1 < NTILES);
    const int boff0 = (nt0 * 16 + ln) * 32 + 8 * qd;
    const int boff1 = (nt1 * 16 + ln) * 32 + 8 * qd;

    int abase[MTILES];
#pragma unroll
    for (int mt = 0; mt < MTILES; ++mt) {
        const int m = mt * 16 + ln;
        abase[mt] = (m < Ssz ? m : Ssz - 1) * PX + 8 * qd;
    }

    bf16x8 bX[5][2], bY[5][2];
    conv_loadB<0>(BtgC, boff0, boff1, has1, bX);
    conv_loadB<1>(BtgC, boff0, boff1, has1, bY);

#pragma unroll
    for (int es = 0; es < 2; ++es) {
        const float* in_g = essays + (size_t)(be0 + es) * (Ssz * Dsz);
        float4 va[9], vb[9];
        int rr[9], cc[9];
        bool hv[9], fv[9], gv[9];
#pragma unroll
        for (int it = 0; it < 9; ++it) {
            const int g  = tid + it * 256;
            const int r  = g / 41;
            const int c8 = (g - r * 41) * 8;
            const int s  = r - 2;
            gv[it] = (g < NGRP);
            hv[it] = gv[it] && (s >= 0) && (s < Ssz) && (c8 < Dsz);
            fv[it] = hv[it] && (c8 + 8 <= Dsz);
            const float* base = in_g + (hv[it] ? (s * Dsz + c8) : 0);
            va[it] = *reinterpret_cast<const float4*>(base);
            vb[it] = *reinterpret_cast<const float4*>(fv[it] ? base + 4 : base);
            rr[it] = r; cc[it] = c8;
        }
#pragma unroll
        for (int it = 0; it < 9; ++it) {
            if (!gv[it]) continue;
            const float e0 = hv[it] ? va[it].x : 0.f;
            const float e1 = hv[it] ? va[it].y : 0.f;
            const float e2 = hv[it] ? va[it].z : 0.f;
            const float e3 = hv[it] ? va[it].w : 0.f;
            const float e4 = fv[it] ? vb[it].x : 0.f;
            const float e5 = fv[it] ? vb[it].y : 0.f;
            const float e6 = fv[it] ? vb[it].z : 0.f;
            const float e7 = fv[it] ? vb[it].w : 0.f;
            uint4 o;
            o.x = f2bf2(e0, e1);
            o.y = f2bf2(e2, e3);
            o.z = f2bf2(e4, e5);
            o.w = f2bf2(e6, e7);
            *reinterpret_cast<uint4*>(&buf[es][rr[it] * PX + cc[it]]) = o;
        }
    }
    __syncthreads();

    const unsigned short* b0p = buf[0];
    const unsigned short* b1p = buf[1];

    f32x4 acc[2][MTILES][2];
#pragma unroll
    for (int es = 0; es < 2; ++es)
#pragma unroll
        for (int mt = 0; mt < MTILES; ++mt) { acc[es][mt][0] = (f32x4)0.f; acc[es][mt][1] = (f32x4)0.f; }

    {
        bf16x8 aX[2][MTILES], aY[2][MTILES];
        conv_loadA<0>(b0p, b1p, abase, aX);
        conv_group<0>(b0p, b1p, abase, has1, bX, aX, aY, acc);
        conv_loadB<2>(BtgC, boff0, boff1, has1, bX);
        conv_group<1>(b0p, b1p, abase, has1, bY, aX, aY, acc);
        conv_loadB<3>(BtgC, boff0, boff1, has1, bY);
        conv_group<2>(b0p, b1p, abase, has1, bX, aX, aY, acc);
        conv_loadB<4>(BtgC, boff0, boff1, has1, bX);
        conv_group<3>(b0p, b1p, abase, has1, bY, aX, aY, acc);
        conv_loadB<5>(BtgC, boff0, boff1, has1, bY);
        conv_group<4>(b0p, b1p, abase, has1, bX, aX, aY, acc);
        conv_loadB<6>(BtgC, boff0, boff1, has1, bX);
        conv_group<5>(b0p, b1p, abase, has1, bY, aX, aY, acc);
        conv_loadB<7>(BtgC, boff0, boff1, has1, bY);
        conv_group<6>(b0p, b1p, abase, has1, bX, aX, aY, acc);
        conv_loadB<8>(BtgC, boff0, boff1, has1, bX);
        conv_group<7>(b0p, b1p, abase, has1, bY, aX, aY, acc);
        conv_loadB<9>(BtgC, boff0, boff1, has1, bY);
        conv_group<8>(b0p, b1p, abase, has1, bX, aX, aY, acc);
        conv_group<9>(b0p, b1p, abase, has1, bY, aX, aY, acc);
    }

    bf16x8 a1b[4][2];
#pragma unroll
    for (int kt = 0; kt < 4; ++kt) {
        a1b[kt][0] = *reinterpret_cast<const bf16x8*>(BtgA + kt * 3584 + boff0);
        a1b[kt][1] = has1 ? *reinterpret_cast<const bf16x8*>(BtgA + kt * 3584 + boff1)
                          : (bf16x8)0;
    }
    __syncthreads();

    {
        const float bias0 = conv_b[nt0 * 16 + ln];
        const int n_g1 = nt1 * 16 + ln;
        const bool g1ok = has1 && (n_g1 < Fsz);
        const float bias1 = g1ok ? conv_b[n_g1] : 0.f;
#pragma unroll
        for (int es = 0; es < 2; ++es) {
#pragma unroll
            for (int mt = 0; mt < MTILES; ++mt) {
#pragma unroll
                for (int j = 0; j < 4; ++j) {
                    const int m_row = mt * 16 + qd * 4 + j;
                    buf[es][m_row * PC + nt0 * 16 + ln] = f2bf(fmaxf(acc[es][mt][0][j] + bias0, 0.f));
                    if (g1ok)
                        buf[es][m_row * PC + n_g1] = f2bf(fmaxf(acc[es][mt][1][j] + bias1, 0.f));
                }
            }
        }
    }
    for (int idx = tid; idx < 2 * 64 * 2; idx += 256) {
        const int es = idx >> 7;
        const int r2 = idx & 127;
        const int row = r2 >> 1;
        const int c = 112 + (r2 & 1) * 8;
        *reinterpret_cast<u16x8*>(&buf[es][row * PC + c]) = (u16x8)0;
    }
    __syncthreads();

    f32x4 acc2[2][MTILES][2];
#pragma unroll
    for (int es = 0; es < 2; ++es)
#pragma unroll
        for (int mt = 0; mt < MTILES; ++mt) { acc2[es][mt][0] = (f32x4)0.f; acc2[es][mt][1] = (f32x4)0.f; }

    {
        int abase2[MTILES];
#pragma unroll
        for (int mt = 0; mt < MTILES; ++mt) abase2[mt] = (mt * 16 + ln) * PC + 8 * qd;

        bf16x8 aX[2][MTILES], aY[2][MTILES];
        att_loadA<0>(b0p, b1p, abase2, aX);
        att_loadA<1>(b0p, b1p, abase2, aY);
        mfma16(aX, a1b[0], has1, acc2);
        att_loadA<2>(b0p, b1p, abase2, aX);
        mfma16(aY, a1b[1], has1, acc2);
        att_loadA<3>(b0p, b1p, abase2, aY);
        mfma16(aX, a1b[2], has1, acc2);
        mfma16(aY, a1b[3], has1, acc2);
    }

    {
        const int g0 = nt0 * 16 + ln;
        const float b1v0 = att1_bias[g0];
        const float vv0  = att1_vec[g0];
        const int g1 = nt1 * 16 + ln;
        const bool g1v = has1 && (g1 < Fsz);
        const float b1v1 = g1v ? att1_bias[g1] : 0.f;
        const float vv1  = g1v ? att1_vec[g1]  : 0.f;
#pragma unroll
        for (int es = 0; es < 2; ++es) {
#pragma unroll
            for (int mt = 0; mt < MTILES; ++mt) {
#pragma unroll
                for (int j = 0; j < 4; ++j) {
                    const int m_row = mt * 16 + qd * 4 + j;
                    float val = 0.f;
                    if (m_row < Ssz) {
                        val = tanhf_fast(acc2[es][mt][0][j] + b1v0) * vv0;
                        if (g1v) val += tanhf_fast(acc2[es][mt][1][j] + b1v1) * vv1;
                    }
                    val += __shfl_xor(val, 1);
                    val += __shfl_xor(val, 2);
                    val += __shfl_xor(val, 4);
                    val += __shfl_xor(val, 8);
                    if (ln == 0 && m_row < Ssz) atomicAdd(&u_s[es][m_row], val);
                }
            }
        }
    }
    __syncthreads();

    if (wid < 2) {
        const float uv = (lane < Ssz) ? u_s[wid][lane] : -1e30f;
        float m = uv;
#pragma unroll
        for (int off = 32; off > 0; off >>= 1) m = fmaxf(m, __shfl_xor(m, off));
        float e = (lane < Ssz) ? __expf(uv - m) : 0.f;
        float sum = e;
#pragma unroll
        for (int off = 32; off > 0; off >>= 1) sum += __shfl_xor(sum, off);
        alpha_s[wid][lane] = e / sum;
    }
    __syncthreads();

    {
        const int es = tid >> 7;
        const int f  = tid & 127;
        unsigned short v = 0;
        if (f < Fsz) {
            float a = 0.f;
            for (int s = 0; s < Ssz; ++s) a += alpha_s[es][s] * bf2f(buf[es][s * PC + f]);
            v = f2bf(a);
        }
        sent_bf[(size_t)(be0 + es) * 128 + f] = v;
    }
}

// ---------------------------------------------------------------------------
// Kernel 1b: xpartB[row*400 + gi] = sent_bf @ Wx + lstm_b, row = b*64+t,
// gi = cell*4+gate (quad-interleaved, matches lstm tid order)
// ---------------------------------------------------------------------------
__global__ __launch_bounds__(256) void xpart_kernel(
    const unsigned short* __restrict__ sent_bf, // [2048][128]
    const unsigned short* __restrict__ BtgW,    // [4][400][32] (std gate order)
    const float* __restrict__ lstm_b,           // [400]
    float* __restrict__ xpartB)                 // [2048][400] (b*64+t, gi)
{
    const int wid  = threadIdx.x >> 6;
    const int mt   = blockIdx.x * 4 + wid;      // 0..127
    const int lane = threadIdx.x & 63;
    const int ln   = lane & 15;
    const int qd   = lane >> 4;
    const int m0   = mt * 16;

    f32x4 acc[25];
#pragma unroll
    for (int nt = 0; nt < 25; ++nt) acc[nt] = (f32x4)0.f;

#pragma unroll
    for (int kt = 0; kt < 4; ++kt) {
        const bf16x8 a = *reinterpret_cast<const bf16x8*>(
            sent_bf + (size_t)(m0 + ln) * 128 + kt * 32 + 8 * qd);
#pragma unroll
        for (int nt = 0; nt < 25; ++nt) {
            const bf16x8 b = *reinterpret_cast<const bf16x8*>(
                BtgW + ((size_t)kt * 400 + nt * 16 + ln) * 32 + 8 * qd);
            acc[nt] = __builtin_amdgcn_mfma_f32_16x16x32_bf16(a, b, acc[nt], 0, 0, 0);
        }
    }

#pragma unroll
    for (int nt = 0; nt < 25; ++nt) {
        const int col = nt * 16 + ln;               // standard gate order
        const int gate = col / 100;
        const int cell = col - gate * 100;
        const float bias = lstm_b[col];
        const int gi = cell * 4 + gate;
#pragma unroll
        for (int j = 0; j < 4; ++j) {
            const int row = m0 + qd * 4 + j;        // b*64 + t
            xpartB[(size_t)row * 400 + gi] = acc[nt][j] + bias;
        }
    }
}

// ---------------------------------------------------------------------------
// Kernel 2: fused LSTM + att2, one block per batch. No global ops in loop;
// f16-packed gate dot (13 b128 h reads + 52 v_dot2 per thread-step),
// DPP quad-exchange (VALU, no LDS), 1 barrier/step.
// tid = 4*cell + gate (gate: 0=i,1=j,2=f,3=o); threads 0..399 active.
// ---------------------------------------------------------------------------
__global__ __launch_bounds__(448) void lstm_att2_kernel(
    const float* __restrict__ xpartB,    // [2048][400] (b*64+t, gi) +bias
    const unsigned int* __restrict__ BtgP, // [52][400] Wh half2-packed
    const float* __restrict__ att2_mat,  // [H,H]
    const float* __restrict__ att2_bias, // [H]
    const float* __restrict__ att2_vec,  // [H]
    const float* __restrict__ dense_w,   // [H]
    const float* __restrict__ dense_b,   // [1]
    float* __restrict__ out)             // [B]
{
    __shared__ __align__(16) float xp_lds[Esz * 400];        // 102400 B
    __shared__ __align__(16) float hist[Esz * Hsz];          // 25600 B
    __shared__ __align__(16) unsigned short h16[2][104];     // 416 B (f16 h, dbuf)
    __shared__ float u2_s[Esz];
    __shared__ float alpha2_s[Esz];
    __shared__ float repr_s[Hsz];

    const int b   = blockIdx.x;
    const int tid = threadIdx.x;
    const bool actv = tid < 400;
    const int cell = tid >> 2;
    const int g    = tid & 3;

    // ---- stage xpart for this batch into LDS (6400 float4, coalesced) ----
    {
        const float4* src = reinterpret_cast<const float4*>(xpartB + (size_t)b * Esz * 400);
        float4* dst = reinterpret_cast<float4*>(xp_lds);
        for (int i = tid; i < Esz * 100; i += 448) dst[i] = src[i];
    }

    // ---- packed Wh column (52 half2 pairs) into registers, coalesced ----
    unsigned int wp[52];
    if (actv) {
#pragma unroll
        for (int q = 0; q < 52; ++q) wp[q] = BtgP[q * 400 + tid];
    }
    // zero both h16 buffers (incl. pads 100..103)
    if (tid < 104) { h16[0][tid] = 0; h16[1][tid] = 0; }
    float c = 0.f;
    __syncthreads();

    // ---- recurrence: 1 barrier/step, no global ops, no LDS shuffles ----
    for (int t = 0; t < Esz; ++t) {
        if (actv) {
            const uint4* hq = reinterpret_cast<const uint4*>(h16[t & 1]);
            float za = xp_lds[t * 400 + tid], zb = 0.f, zc = 0.f, zd = 0.f;
#pragma unroll
            for (int q = 0; q < 13; ++q) {
                const uint4 hv = hq[q];
                UH32 h0, h1, h2, h3, w0, w1, w2, w3;
                h0.u = hv.x; h1.u = hv.y; h2.u = hv.z; h3.u = hv.w;
                w0.u = wp[4 * q + 0]; w1.u = wp[4 * q + 1];
                w2.u = wp[4 * q + 2]; w3.u = wp[4 * q + 3];
                za = __builtin_amdgcn_fdot2(w0.v, h0.v, za, false);
                zb = __builtin_amdgcn_fdot2(w1.v, h1.v, zb, false);
                zc = __builtin_amdgcn_fdot2(w2.v, h2.v, zc, false);
                zd = __builtin_amdgcn_fdot2(w3.v, h3.v, zd, false);
            }
            const float z = (za + zb) + (zc + zd);

            // quad exchange via DPP (VALU; quads fully active, never straddle waves)
            const float zi = dpp_bcast(z, 0);
            const float zj = dpp_bcast(z, 1);
            const float zf = dpp_bcast(z, 2);
            const float zo = dpp_bcast(z, 3);

            c = c * sigmoid_fast(zf + 1.0f) + sigmoid_fast(zi) * tanhf_fast(zj);
            const float h = sigmoid_fast(zo) * tanhf_fast(c);
            if (g == 0) {
                UH16 cv; cv.h = (_Float16)h;
                h16[(t + 1) & 1][cell] = cv.u;
                hist[t * Hsz + cell] = h;
            }
        }
        __syncthreads();
    }

    // ---- att2 on LDS hist; w2 aliases xp_lds (dead after recurrence) ----
    float* w2_s = xp_lds;
    for (int idx = tid; idx < Esz * Hsz; idx += 448) {
        const int e = idx / Hsz;
        const int gg = idx - e * Hsz;
        const float* lp = hist + e * Hsz;
        float a0 = 0.f, a1 = 0.f, a2 = 0.f, a3 = 0.f;
        for (int k = 0; k < Hsz; k += 4) {
            a0 += lp[k + 0] * att2_mat[(k + 0) * Hsz + gg];
            a1 += lp[k + 1] * att2_mat[(k + 1) * Hsz + gg];
            a2 += lp[k + 2] * att2_mat[(k + 2) * Hsz + gg];
            a3 += lp[k + 3] * att2_mat[(k + 3) * Hsz + gg];
        }
        w2_s[idx] = tanhf_fast(att2_bias[gg] + ((a0 + a1) + (a2 + a3))) * att2_vec[gg];
    }
    __syncthreads();

    if (tid < Esz) {
        float acc = 0.f;
        const float* wpp = w2_s + tid * Hsz;
        for (int gg = 0; gg < Hsz; ++gg) acc += wpp[gg];
        u2_s[tid] = acc;
    }
    __syncthreads();

    if (tid < 64) {
        const float uv = u2_s[tid];
        float m = uv;
#pragma unroll
        for (int off = 32; off > 0; off >>= 1) m = fmaxf(m, __shfl_xor(m, off));
        float e = __expf(uv - m);
        float sum = e;
#pragma unroll
        for (int off = 32; off > 0; off >>= 1) sum += __shfl_xor(sum, off);
        alpha2_s[tid] = e / sum;
    }
    __syncthreads();

    if (tid < Hsz) {
        float acc = 0.f;
        for (int e = 0; e < Esz; ++e) acc += alpha2_s[e] * hist[e * Hsz + tid];
        repr_s[tid] = acc;
    }
    __syncthreads();

    if (tid == 0) {
        float acc = dense_b[0];
        for (int hh = 0; hh < Hsz; ++hh) acc += repr_s[hh] * dense_w[hh];
        out[b] = sigmoid_fast(acc);
    }
}

// ---------------------------------------------------------------------------
extern "C" void kernel_launch(void* const* d_in, const int* in_sizes, int n_in,
                              void* d_out, int out_size, void* d_ws, size_t ws_size,
                              hipStream_t stream) {
    const float* essays    = (const float*)d_in[0];
    const float* conv_k    = (const float*)d_in[1];
    const float* conv_b    = (const float*)d_in[2];
    const float* att1_mat  = (const float*)d_in[3];
    const float* att1_bias = (const float*)d_in[4];
    const float* att1_vec  = (const float*)d_in[5];
    const float* lstm_W    = (const float*)d_in[6];
    const float* lstm_b    = (const float*)d_in[7];
    const float* att2_mat  = (const float*)d_in[8];
    const float* att2_bias = (const float*)d_in[9];
    const float* att2_vec  = (const float*)d_in[10];
    const float* dense_w   = (const float*)d_in[11];
    const float* dense_b   = (const float*)d_in[12];

    float* out = (float*)d_out;

    // workspace layout (256B-aligned chunks)
    char* ws = (char*)d_ws;
    unsigned short* sent_bf = (unsigned short*)ws;              // 524288 B
    float* xpartB = (float*)(ws + 524288);                      // 3276800 B
    unsigned short* BtgC = (unsigned short*)(ws + 3801088);     // 358400 B
    unsigned short* BtgA = (unsigned short*)(ws + 4159488);     // 28672 B
    unsigned short* BtgW = (unsigned short*)(ws + 4188160);     // 102400 B
    unsigned int*   BtgP = (unsigned int*)(ws + 4290560);       // 83200 B

    prep_kernel<<<512, 256, 0, stream>>>(conv_k, att1_mat, lstm_W, BtgC, BtgA, BtgW, BtgP);
    conv_att1_kernel<<<Bsz * Esz / 2, 256, 0, stream>>>(
        essays, BtgC, BtgA, conv_b, att1_bias, att1_vec, sent_bf);
    xpart_kernel<<<32, 256, 0, stream>>>(sent_bf, BtgW, lstm_b, xpartB);
    lstm_att2_kernel<<<Bsz, 448, 0, stream>>>(
        xpartB, BtgP, att2_mat, att2_bias, att2_vec, dense_w, dense_b, out);
}